// Round 13
// baseline (439.849 us; speedup 1.0000x reference)
//
#include <hip/hip_runtime.h>
#include <hip/hip_bf16.h>

typedef __attribute__((ext_vector_type(4))) float f32x4;
typedef __attribute__((ext_vector_type(8))) short s16x8;

#define NB 4
#define CHN 128
#define HH 256
#define WW 256
#define HWSZ (HH*WW)                            // 65536
#define TENSOR_ELEMS ((size_t)NB*CHN*HWSZ)      // 33,554,432
#define SCALE 0.08838834764831845f              // 1/sqrt(128)

__device__ __forceinline__ unsigned short f2b(float f) {
    unsigned int u = __builtin_bit_cast(unsigned int, f);
    u += 0x7fffu + ((u >> 16) & 1u);            // RNE
    return (unsigned short)(u >> 16);
}
__device__ __forceinline__ unsigned int pack2(float a, float b) {
    return (unsigned int)f2b(a) | ((unsigned int)f2b(b) << 16);
}
__device__ __forceinline__ float b2f(unsigned int lo16) {   // low 16 bits = bf16
    return __builtin_bit_cast(float, lo16 << 16);
}

// Load this lane's MFMA A-fragments (16 c_out rows per wave) directly from
// global W (fp32, L2-hot) -> bf16 regs. Mapping verified in R9 (refcheck pass).
__device__ __forceinline__ void load_w_frag(const float* __restrict__ W,
                                            int wave, int lr, int lg, s16x8 af[4]) {
    int arow = wave*16 + lr;
    #pragma unroll
    for (int ks = 0; ks < 4; ++ks) {
        const float4* wp = (const float4*)(W + arow*128 + ks*32 + lg*8);
        float4 a = wp[0], b = wp[1];
        uint4 u;
        u.x = pack2(a.x, a.y); u.y = pack2(a.z, a.w);
        u.z = pack2(b.x, b.y); u.w = pack2(b.z, b.w);
        af[ks] = __builtin_bit_cast(s16x8, u);
    }
}

// 128(c_out) x 128(pos) x 128(K) GEMM, A-fragments in regs, B from LDS
__device__ __forceinline__ void gemm_tile_w(const s16x8 af[4], const uint4* bufB4,
                                            int lr, int lg, f32x4 acc[8]) {
    #pragma unroll
    for (int nt = 0; nt < 8; ++nt) {
        int brow = nt*16 + lr;
        #pragma unroll
        for (int ks = 0; ks < 4; ++ks) {
            s16x8 bf = __builtin_bit_cast(s16x8, bufB4[brow*16 + ((ks*4+lg) ^ (brow & 15))]);
            acc[nt] = __builtin_amdgcn_mfma_f32_16x16x32_bf16(af[ks], bf, acc[nt], 0, 0, 0);
        }
    }
}

__device__ __forceinline__ void epi_nhwc(unsigned short* __restrict__ out, const float* __restrict__ bias,
                                         int n, int pos0, int wave, int lr, int lg, const f32x4 acc[8]) {
    int cb = wave*16 + lg*4;
    float bs[4];
    #pragma unroll
    for (int r = 0; r < 4; ++r) bs[r] = bias[cb + r];
    #pragma unroll
    for (int nt = 0; nt < 8; ++nt) {
        size_t rowb = ((size_t)n*HWSZ + pos0 + nt*16 + lr)*CHN + cb;
        uint2 u;
        u.x = pack2(acc[nt][0]+bs[0], acc[nt][1]+bs[1]);
        u.y = pack2(acc[nt][2]+bs[2], acc[nt][3]+bs[3]);
        *(uint2*)(out + rowb) = u;
    }
}

// Fused: cast/LN + the 2-or-3 channel-mix GEMMs per 128-position tile.
// Weights direct-to-registers (no LDS staging). V-output (NCHW) bounced
// through LDS -> fully coalesced 16B stores. 5 barriers.
__global__ __launch_bounds__(512)
void proj_kernel(const float* __restrict__ msi, const float* __restrict__ pan,
                 const float* __restrict__ lnw_m, const float* __restrict__ lnb_m,
                 const float* __restrict__ lnw_p, const float* __restrict__ lnb_p,
                 const float* __restrict__ w_mp1, const float* __restrict__ b_mp1,
                 const float* __restrict__ w_pp1, const float* __restrict__ b_pp1,
                 const float* __restrict__ w_mp2, const float* __restrict__ b_mp2,
                 const float* __restrict__ w_pp2, const float* __restrict__ b_pp2,
                 unsigned short* __restrict__ ws_u)
{
    __shared__ uint4 pool[2176];    // bufB 32KB (2048 uint4) / vbounce [128c][136p] bf16 (34816B)
    __shared__ float red[1024];
    __shared__ float s_mu[128];
    __shared__ float s_rs[128];

    uint4* bufB4 = pool;
    unsigned short* vbounce = (unsigned short*)pool;

    const int t = threadIdx.x;
    const int isPan = blockIdx.y;
    const int gid = blockIdx.x;                  // 0..2047
    const int n = gid >> 9;
    const int pos0 = (gid & 511) << 7;

    const int pos = t & 127;
    const int cg = t >> 7;                       // 0..3  (32 channels each)

    const float* src = isPan ? pan : msi;
    const float* lnw = isPan ? lnw_p : lnw_m;
    const float* lnb = isPan ? lnb_p : lnb_m;

    unsigned short* q_msi_t = ws_u;
    unsigned short* q_pfm_t = ws_u + TENSOR_ELEMS;
    unsigned short* q_pan_t = ws_u + 2*TENSOR_ELEMS;
    unsigned short* v_msi   = ws_u + 3*TENSOR_ELEMS;
    unsigned short* v_pan   = ws_u + 4*TENSOR_ELEMS;

    const int wave = t >> 6, lane = t & 63, lr = lane & 15, lg = lane >> 4;
    const f32x4 zero4 = {0.f, 0.f, 0.f, 0.f};

    // ---- load raw channel values for this position (kept in registers)
    float vals[32];
    {
        const float* p = src + ((size_t)(n*CHN + cg*32))*HWSZ + pos0 + pos;
        #pragma unroll
        for (int j = 0; j < 32; ++j) vals[j] = p[(size_t)j*HWSZ];
    }
    // ---- V-proj weight fragments (direct from global, L2-hot)
    s16x8 afV[4];
    load_w_frag(isPan ? w_pp2 : w_mp2, wave, lr, lg, afV);

    // raw bf16 tile -> bufB  (B operand: [pos][c])
    #pragma unroll
    for (int k8 = 0; k8 < 4; ++k8) {
        uint4 u;
        u.x = pack2(vals[k8*8+0], vals[k8*8+1]);
        u.y = pack2(vals[k8*8+2], vals[k8*8+3]);
        u.z = pack2(vals[k8*8+4], vals[k8*8+5]);
        u.w = pack2(vals[k8*8+6], vals[k8*8+7]);
        int chunk = cg*4 + k8;
        bufB4[pos*16 + (chunk ^ (pos & 15))] = u;
    }
    __syncthreads();                              // B1: bufB staged

    // ---- GEMM 1: V projection on raw input
    f32x4 acc[8];
    #pragma unroll
    for (int i = 0; i < 8; ++i) acc[i] = zero4;
    gemm_tile_w(afV, bufB4, lr, lg, acc);

    // ---- LN partial sums (independent LDS region)
    float s = 0.f, q = 0.f;
    #pragma unroll
    for (int j = 0; j < 32; ++j) { s += vals[j]; q += vals[j]*vals[j]; }
    red[t] = s; red[512 + t] = q;
    __syncthreads();                              // B2: GEMM1 bufB reads done + red ready

    // ---- stats + bounce V output into pool as [128c][136p] bf16
    if (t < 128) {
        float S = red[t] + red[t+128] + red[t+256] + red[t+384];
        float Q = red[512+t] + red[512+t+128] + red[512+t+256] + red[512+t+384];
        float mu = S * (1.0f/128.0f);
        float var = Q * (1.0f/128.0f) - mu*mu;
        s_mu[t] = mu;
        s_rs[t] = rsqrtf(var + 1e-6f);
    }
    {
        const float* bias = isPan ? b_pp2 : b_mp2;
        int cb = wave*16 + lg*4;
        float bs[4];
        #pragma unroll
        for (int r = 0; r < 4; ++r) bs[r] = bias[cb + r];
        #pragma unroll
        for (int nt = 0; nt < 8; ++nt) {
            int p = nt*16 + lr;
            #pragma unroll
            for (int r = 0; r < 4; ++r)
                vbounce[(cb + r)*136 + p] = f2b(acc[nt][r] + bs[r]);
        }
    }
    __syncthreads();                              // B3: vbounce written

    // ---- coalesced V store + normalize vals
    {
        unsigned short* vout = isPan ? v_pan : v_msi;
        #pragma unroll
        for (int i = 0; i < 4; ++i) {
            int fl = i*512 + t;
            int c = fl >> 4, k = fl & 15;
            uint4 u = *(const uint4*)(vbounce + c*136 + k*8);
            *(uint4*)(vout + ((size_t)(n*CHN + c))*HWSZ + pos0 + k*8) = u;
        }
    }
    {
        float mu = s_mu[pos], rs = s_rs[pos];
        #pragma unroll
        for (int j = 0; j < 32; ++j) {
            int c = cg*32 + j;
            vals[j] = (vals[j] - mu) * rs * lnw[c] + lnb[c];
        }
    }
    // ---- Q-proj weight fragments (overlap with V store)
    s16x8 afQ[4];
    load_w_frag(isPan ? w_pp1 : w_mp1, wave, lr, lg, afQ);
    __syncthreads();                              // B4: vbounce reads done -> pool reusable

    // normalized bf16 tile -> bufB
    #pragma unroll
    for (int k8 = 0; k8 < 4; ++k8) {
        uint4 u;
        u.x = pack2(vals[k8*8+0], vals[k8*8+1]);
        u.y = pack2(vals[k8*8+2], vals[k8*8+3]);
        u.z = pack2(vals[k8*8+4], vals[k8*8+5]);
        u.w = pack2(vals[k8*8+6], vals[k8*8+7]);
        int chunk = cg*4 + k8;
        bufB4[pos*16 + (chunk ^ (pos & 15))] = u;
    }
    __syncthreads();                              // B5: normalized bufB staged

    // ---- GEMM 2: Q projection on normalized input -> NHWC bf16
    #pragma unroll
    for (int i = 0; i < 8; ++i) acc[i] = zero4;
    gemm_tile_w(afQ, bufB4, lr, lg, acc);
    epi_nhwc(isPan ? q_pan_t : q_msi_t, isPan ? b_pp1 : b_mp1, n, pos0, wave, lr, lg, acc);

    if (!isPan) {
        // ---- GEMM 3 (msi only): pan_proj1(norm_msi) quirk -> q_pfm, NHWC bf16
        //      no barriers: new A-frags in regs, bufB unchanged
        s16x8 af3[4];
        load_w_frag(w_pp1, wave, lr, lg, af3);
        #pragma unroll
        for (int i = 0; i < 8; ++i) acc[i] = zero4;
        gemm_tile_w(af3, bufB4, lr, lg, acc);
        epi_nhwc(q_pfm_t, b_pp1, n, pos0, wave, lr, lg, acc);
    }
}

// R7 structure with 4-bit XOR swizzles (conflict-free 16-lane column reads):
//  - S^T QK^T (swapped mfma operands), 2-shuffle softmax, scalar m/l
//  - P rows wave-local: packed uint2 P-stores, NO barrier before PV
//  - 1/l folded into O-bounce; coalesced epilogue
// Barriers: B1(stage) -> QKT+Vstage+softmax -> B2 -> Pwrite+PV -> B3 -> bounce -> B4 -> epi
__global__ __launch_bounds__(512, 2)
void attn_kernel(const unsigned short* __restrict__ ws_u,
                 const float* __restrict__ msi, const float* __restrict__ pan,
                 const float* __restrict__ beta, const float* __restrict__ gamma,
                 float* __restrict__ out)
{
    __shared__ uint4 kp4[4096];     // K [256v][128c] -> P [128w][256v] -> O bounce
    __shared__ uint4 v4[4096];      // V [128c][256v] bf16

    const int t = threadIdx.x;
    const int wave = t >> 6, lane = t & 63, lr = lane & 15, lg = lane >> 4;
    // grid remap: the 4 sibling blocks of an nh land on the SAME XCD (bid%8)
    const int bid = blockIdx.x;
    const int sib = (bid >> 3) & 3;
    const int nh = (bid >> 5) * 8 + (bid & 7);   // 0..1023
    const int path = sib >> 1;
    const int wh = sib & 1;
    const int n = nh >> 8, h = nh & 255;

    const unsigned short* q_msi_t = ws_u;
    const unsigned short* q_pfm_t = ws_u + TENSOR_ELEMS;
    const unsigned short* q_pan_t = ws_u + 2*TENSOR_ELEMS;
    const unsigned short* v_msi   = ws_u + 3*TENSOR_ELEMS;
    const unsigned short* v_pan   = ws_u + 4*TENSOR_ELEMS;

    const unsigned short* Qp = path ? q_pfm_t : q_msi_t;
    const unsigned short* Kp = path ? q_msi_t : q_pan_t;
    const unsigned short* Vp = path ? v_msi   : v_pan;
    const float* resid = path ? pan : msi;
    const float* mul   = path ? gamma : beta;
    float* outp = out + (path ? TENSOR_ELEMS : (size_t)0);

    const size_t qkBase = (size_t)nh * (256*128);   // NHWC row base (elements)
    const unsigned short* vb = Vp + (size_t)n*CHN*HWSZ + (size_t)h*WW;  // V rows (NCHW)

    // ---- stage K (contiguous 64KB) into swizzled LDS
    {
        const uint4* g = (const uint4*)(Kp + qkBase);
        #pragma unroll
        for (int it = 0; it < 8; ++it) {
            int i = it*512 + t;
            int v = i >> 4, ch = i & 15;
            kp4[v*16 + (ch ^ (v & 15))] = g[i];
        }
    }
    // ---- Q fragments: global -> regs (wave owns 16 query positions)
    s16x8 qf[4];
    {
        int w = wh*128 + wave*16 + lr;
        const uint4* g = (const uint4*)(Qp + qkBase + (size_t)w*128);
        #pragma unroll
        for (int ks = 0; ks < 4; ++ks) qf[ks] = __builtin_bit_cast(s16x8, g[ks*4 + lg]);
    }
    __syncthreads();

    // ---- S^T = K Q^T  (wave: 256 v x its 16 w); lane holds S[w=lane&15][v=nt*16+lg*4+r]
    const f32x4 zero4 = {0.f, 0.f, 0.f, 0.f};
    f32x4 sAcc[16];
    #pragma unroll
    for (int i = 0; i < 16; ++i) sAcc[i] = zero4;
    #pragma unroll
    for (int nt = 0; nt < 16; ++nt) {
        int vrow = nt*16 + lr;
        #pragma unroll
        for (int ks = 0; ks < 4; ++ks) {
            s16x8 kf = __builtin_bit_cast(s16x8, kp4[vrow*16 + ((ks*4+lg) ^ (vrow & 15))]);
            sAcc[nt] = __builtin_amdgcn_mfma_f32_16x16x32_bf16(kf, qf[ks], sAcc[nt], 0, 0, 0);
        }
    }

    // ---- stage V into independent region (loads overlap softmax)
    {
        #pragma unroll
        for (int it = 0; it < 8; ++it) {
            int i = it*512 + t;
            int c = i >> 5, ch = i & 31;
            const uint4* g = (const uint4*)(vb + (size_t)c*HWSZ + ch*8);
            v4[c*32 + (ch ^ (c & 15))] = g[0];
        }
    }

    // ---- prefetch residual (fp32, fully coalesced float4) -> 32 regs
    f32x4 rsdA[4], rsdB[4];
    {
        const float* rb = resid + (size_t)n*CHN*HWSZ + (size_t)h*WW + wh*128;
        #pragma unroll
        for (int i = 0; i < 4; ++i) {
            int fl = i*512 + t;
            int c = fl >> 4, k = fl & 15;
            const float* p = rb + (size_t)c*HWSZ + k*8;
            rsdA[i] = *(const f32x4*)p;
            rsdB[i] = *(const f32x4*)(p + 4);
        }
    }

    // ---- softmax over v (lane's own column w = lane&15): scalar m/l, 2 shuffles
    float mx = -1e30f;
    #pragma unroll
    for (int nt = 0; nt < 16; ++nt) {
        #pragma unroll
        for (int r = 0; r < 4; ++r) mx = fmaxf(mx, sAcc[nt][r]);
    }
    mx = fmaxf(mx, __shfl_xor(mx, 16, 64));
    mx = fmaxf(mx, __shfl_xor(mx, 32, 64));
    float sm = 0.f;
    #pragma unroll
    for (int nt = 0; nt < 16; ++nt) {
        #pragma unroll
        for (int r = 0; r < 4; ++r) {
            float p = __expf((sAcc[nt][r] - mx) * SCALE);
            sAcc[nt][r] = p;
            sm += p;
        }
    }
    sm += __shfl_xor(sm, 16, 64);
    sm += __shfl_xor(sm, 32, 64);
    const float inv = 1.0f / sm;

    __syncthreads();                 // QKT reads done (kp4 free) + V staged

    // ---- P (un-normalized) -> own-wave LDS slice: 16 packed uint2 stores
    //      elem = (w*256 + v) ^ ((w&15)<<3), v = nt*16 + lg*4 (+r in-pack)
    {
        unsigned short* pbuf = (unsigned short*)kp4;
        const int wloc = wave*16 + lr;            // this lane's w row
        const int pb_base = wloc*256 + lg*4;
        const int sw = lr << 3;                   // (wloc & 15) << 3
        #pragma unroll
        for (int nt = 0; nt < 16; ++nt) {
            uint2 u;
            u.x = pack2(sAcc[nt][0], sAcc[nt][1]);
            u.y = pack2(sAcc[nt][2], sAcc[nt][3]);
            *(uint2*)(pbuf + ((pb_base + nt*16) ^ sw)) = u;
        }
    }
    // NO barrier: each wave reads only its own P rows (in-wave lgkmcnt ordering)

    // ---- O = V * P^T  (wave: all 128 c x its 16 w, K=256)
    f32x4 oAcc[8];
    #pragma unroll
    for (int i = 0; i < 8; ++i) oAcc[i] = zero4;
    const int wrow = wave*16 + lr;
    #pragma unroll
    for (int ks = 0; ks < 8; ++ks) {
        s16x8 pb = __builtin_bit_cast(s16x8, kp4[wrow*32 + ((ks*4+lg) ^ (wrow & 15))]);
        #pragma unroll
        for (int mt = 0; mt < 8; ++mt) {
            int crow = mt*16 + lr;
            s16x8 av = __builtin_bit_cast(s16x8, v4[crow*32 + ((ks*4+lg) ^ (crow & 15))]);
            oAcc[mt] = __builtin_amdgcn_mfma_f32_16x16x32_bf16(av, pb, oAcc[mt], 0, 0, 0);
        }
    }
    __syncthreads();                 // all PV reads done -> reuse kp4 as O bounce

    // ---- bounce O -> LDS [128c][136w] bf16 (1/l folded in here)
    {
        unsigned short* obuf = (unsigned short*)kp4;
        int wloc = wave*16 + lr;     // 0..127 within this block-half
        #pragma unroll
        for (int mt = 0; mt < 8; ++mt) {
            int cb = mt*16 + lg*4;
            #pragma unroll
            for (int r = 0; r < 4; ++r)
                obuf[(cb + r)*136 + wloc] = f2b(oAcc[mt][r] * inv);
        }
    }
    __syncthreads();

    // ---- coalesced epilogue: out = resid + O * mul[c]
    {
        const unsigned short* obuf = (const unsigned short*)kp4;
        float* ob = outp + (size_t)n*CHN*HWSZ + (size_t)h*WW + wh*128;
        #pragma unroll
        for (int i = 0; i < 4; ++i) {
            int fl = i*512 + t;
            int c = fl >> 4, k = fl & 15;
            uint4 u = *(const uint4*)(obuf + c*136 + k*8);
            float mc = mul[c];
            f32x4 o0, o1;
            o0[0] = rsdA[i][0] + b2f(u.x & 0xffffu) * mc;
            o0[1] = rsdA[i][1] + b2f(u.x >> 16) * mc;
            o0[2] = rsdA[i][2] + b2f(u.y & 0xffffu) * mc;
            o0[3] = rsdA[i][3] + b2f(u.y >> 16) * mc;
            o1[0] = rsdB[i][0] + b2f(u.z & 0xffffu) * mc;
            o1[1] = rsdB[i][1] + b2f(u.z >> 16) * mc;
            o1[2] = rsdB[i][2] + b2f(u.w & 0xffffu) * mc;
            o1[3] = rsdB[i][3] + b2f(u.w >> 16) * mc;
            float* p = ob + (size_t)c*HWSZ + k*8;
            *(f32x4*)p = o0;
            *(f32x4*)(p + 4) = o1;
        }
    }
}

extern "C" void kernel_launch(void* const* d_in, const int* in_sizes, int n_in,
                              void* d_out, int out_size, void* d_ws, size_t ws_size,
                              hipStream_t stream) {
    (void)in_sizes; (void)n_in; (void)out_size; (void)ws_size;
    const float* msi   = (const float*)d_in[0];
    const float* pan   = (const float*)d_in[1];
    const float* lnw_m = (const float*)d_in[2];
    const float* lnb_m = (const float*)d_in[3];
    const float* lnw_p = (const float*)d_in[4];
    const float* lnb_p = (const float*)d_in[5];
    const float* w_mp1 = (const float*)d_in[6];
    const float* b_mp1 = (const float*)d_in[7];
    const float* w_pp1 = (const float*)d_in[8];
    const float* b_pp1 = (const float*)d_in[9];
    const float* w_mp2 = (const float*)d_in[10];
    const float* b_mp2 = (const float*)d_in[11];
    const float* w_pp2 = (const float*)d_in[12];
    const float* b_pp2 = (const float*)d_in[13];
    const float* beta  = (const float*)d_in[14];
    const float* gamma = (const float*)d_in[15];
    unsigned short* ws_u = (unsigned short*)d_ws;
    float* out = (float*)d_out;

    proj_kernel<<<dim3(2048, 2), 512, 0, stream>>>(
        msi, pan, lnw_m, lnb_m, lnw_p, lnb_p,
        w_mp1, b_mp1, w_pp1, b_pp1, w_mp2, b_mp2, w_pp2, b_pp2, ws_u);
    attn_kernel<<<dim3(4096), 512, 0, stream>>>(
        ws_u, msi, pan, beta, gamma, out);
}

// Round 14
// 376.981 us; speedup vs baseline: 1.1668x; 1.1668x over previous
//
#include <hip/hip_runtime.h>
#include <hip/hip_bf16.h>

typedef __attribute__((ext_vector_type(4))) float f32x4;
typedef __attribute__((ext_vector_type(8))) short s16x8;

#define NB 4
#define CHN 128
#define HH 256
#define WW 256
#define HWSZ (HH*WW)                            // 65536
#define TENSOR_ELEMS ((size_t)NB*CHN*HWSZ)      // 33,554,432
#define SCALE 0.08838834764831845f              // 1/sqrt(128)

__device__ __forceinline__ unsigned short f2b(float f) {
    unsigned int u = __builtin_bit_cast(unsigned int, f);
    u += 0x7fffu + ((u >> 16) & 1u);            // RNE
    return (unsigned short)(u >> 16);
}
__device__ __forceinline__ unsigned int pack2(float a, float b) {
    return (unsigned int)f2b(a) | ((unsigned int)f2b(b) << 16);
}
__device__ __forceinline__ float b2f(unsigned int lo16) {   // low 16 bits = bf16
    return __builtin_bit_cast(float, lo16 << 16);
}

// Stage a 128x128 fp32 weight matrix -> LDS bf16 [o][cin], 4-bit-XOR swizzled 16B chunks
// (coalesced: consecutive threads read consecutive 32B of W)
__device__ __forceinline__ void stage_w(uint4* bufW4, const float* __restrict__ W, int t) {
    #pragma unroll
    for (int it = 0; it < 4; ++it) {
        int j = it*512 + t;                     // chunk id 0..2047
        int o = j >> 4, ch = j & 15;
        const float4* wp = (const float4*)(W + o*128 + ch*8);
        float4 a = wp[0], b = wp[1];
        uint4 u;
        u.x = pack2(a.x, a.y); u.y = pack2(a.z, a.w);
        u.z = pack2(b.x, b.y); u.w = pack2(b.z, b.w);
        bufW4[o*16 + (ch ^ (o & 15))] = u;
    }
}

// 128(c_out) x 128(pos) x 128(K) GEMM, 8 waves, wave = one 16-row m-tile
__device__ __forceinline__ void gemm_tile(const uint4* bufW4, const uint4* bufB4,
                                          int wave, int lr, int lg, f32x4 acc[8]) {
    s16x8 af[4];
    int arow = wave*16 + lr;
    #pragma unroll
    for (int ks = 0; ks < 4; ++ks)
        af[ks] = __builtin_bit_cast(s16x8, bufW4[arow*16 + ((ks*4+lg) ^ (arow & 15))]);
    #pragma unroll
    for (int nt = 0; nt < 8; ++nt) {
        int brow = nt*16 + lr;
        #pragma unroll
        for (int ks = 0; ks < 4; ++ks) {
            s16x8 bf = __builtin_bit_cast(s16x8, bufB4[brow*16 + ((ks*4+lg) ^ (brow & 15))]);
            acc[nt] = __builtin_amdgcn_mfma_f32_16x16x32_bf16(af[ks], bf, acc[nt], 0, 0, 0);
        }
    }
}

__device__ __forceinline__ void epi_nhwc(unsigned short* __restrict__ out, const float* __restrict__ bias,
                                         int n, int pos0, int wave, int lr, int lg, const f32x4 acc[8]) {
    int cb = wave*16 + lg*4;
    float bs[4];
    #pragma unroll
    for (int r = 0; r < 4; ++r) bs[r] = bias[cb + r];
    #pragma unroll
    for (int nt = 0; nt < 8; ++nt) {
        size_t rowb = ((size_t)n*HWSZ + pos0 + nt*16 + lr)*CHN + cb;
        uint2 u;
        u.x = pack2(acc[nt][0]+bs[0], acc[nt][1]+bs[1]);
        u.y = pack2(acc[nt][2]+bs[2], acc[nt][3]+bs[3]);
        *(uint2*)(out + rowb) = u;
    }
}

// Fused: cast/LN + the 2-or-3 channel-mix GEMMs per 128-position tile.
// V-output (NCHW) bounced through LDS -> fully coalesced 16B stores.
__global__ __launch_bounds__(512)
void proj_kernel(const float* __restrict__ msi, const float* __restrict__ pan,
                 const float* __restrict__ lnw_m, const float* __restrict__ lnb_m,
                 const float* __restrict__ lnw_p, const float* __restrict__ lnb_p,
                 const float* __restrict__ w_mp1, const float* __restrict__ b_mp1,
                 const float* __restrict__ w_pp1, const float* __restrict__ b_pp1,
                 const float* __restrict__ w_mp2, const float* __restrict__ b_mp2,
                 const float* __restrict__ w_pp2, const float* __restrict__ b_pp2,
                 unsigned short* __restrict__ ws_u)
{
    __shared__ uint4 pool[4096];    // [0..2048) = bufB (input tile), [2048..4096) = bufW
    __shared__ float red[1024];
    __shared__ float s_mu[128];
    __shared__ float s_rs[128];

    uint4* bufB4 = pool;
    uint4* bufW4 = pool + 2048;
    unsigned short* vbounce = (unsigned short*)pool;   // [128 c][136 p] bf16 (34.8KB)

    const int t = threadIdx.x;
    const int isPan = blockIdx.y;
    const int gid = blockIdx.x;                  // 0..2047
    const int n = gid >> 9;
    const int pos0 = (gid & 511) << 7;

    const int pos = t & 127;
    const int cg = t >> 7;                       // 0..3  (32 channels each)

    const float* src = isPan ? pan : msi;
    const float* lnw = isPan ? lnw_p : lnw_m;
    const float* lnb = isPan ? lnb_p : lnb_m;

    unsigned short* q_msi_t = ws_u;
    unsigned short* q_pfm_t = ws_u + TENSOR_ELEMS;
    unsigned short* q_pan_t = ws_u + 2*TENSOR_ELEMS;
    unsigned short* v_msi   = ws_u + 3*TENSOR_ELEMS;
    unsigned short* v_pan   = ws_u + 4*TENSOR_ELEMS;

    // ---- load raw channel values for this position (kept in registers)
    float vals[32];
    {
        const float* p = src + ((size_t)(n*CHN + cg*32))*HWSZ + pos0 + pos;
        #pragma unroll
        for (int j = 0; j < 32; ++j) vals[j] = p[(size_t)j*HWSZ];
    }
    // raw bf16 tile -> bufB  (B operand: [pos][c])
    #pragma unroll
    for (int k8 = 0; k8 < 4; ++k8) {
        uint4 u;
        u.x = pack2(vals[k8*8+0], vals[k8*8+1]);
        u.y = pack2(vals[k8*8+2], vals[k8*8+3]);
        u.z = pack2(vals[k8*8+4], vals[k8*8+5]);
        u.w = pack2(vals[k8*8+6], vals[k8*8+7]);
        int chunk = cg*4 + k8;
        bufB4[pos*16 + (chunk ^ (pos & 15))] = u;
    }
    stage_w(bufW4, isPan ? w_pp2 : w_mp2, t);
    __syncthreads();

    const int wave = t >> 6, lane = t & 63, lr = lane & 15, lg = lane >> 4;
    const f32x4 zero4 = {0.f, 0.f, 0.f, 0.f};

    // ---- GEMM 1: V projection on raw input
    f32x4 acc[8];
    #pragma unroll
    for (int i = 0; i < 8; ++i) acc[i] = zero4;
    gemm_tile(bufW4, bufB4, wave, lr, lg, acc);

    // ---- LN partial sums (independent LDS region)
    float s = 0.f, q = 0.f;
    #pragma unroll
    for (int j = 0; j < 32; ++j) { s += vals[j]; q += vals[j]*vals[j]; }
    red[t] = s; red[512 + t] = q;
    __syncthreads();                              // GEMM1 LDS reads done + red ready

    // ---- stats + bounce V output into pool as [128c][136p] bf16
    if (t < 128) {
        float S = red[t] + red[t+128] + red[t+256] + red[t+384];
        float Q = red[512+t] + red[512+t+128] + red[512+t+256] + red[512+t+384];
        float mu = S * (1.0f/128.0f);
        float var = Q * (1.0f/128.0f) - mu*mu;
        s_mu[t] = mu;
        s_rs[t] = rsqrtf(var + 1e-6f);
    }
    {
        const float* bias = isPan ? b_pp2 : b_mp2;
        int cb = wave*16 + lg*4;
        float bs[4];
        #pragma unroll
        for (int r = 0; r < 4; ++r) bs[r] = bias[cb + r];
        #pragma unroll
        for (int nt = 0; nt < 8; ++nt) {
            int p = nt*16 + lr;
            #pragma unroll
            for (int r = 0; r < 4; ++r)
                vbounce[(cb + r)*136 + p] = f2b(acc[nt][r] + bs[r]);
        }
    }
    __syncthreads();

    // ---- coalesced V store + normalize vals
    {
        unsigned short* vout = isPan ? v_pan : v_msi;
        #pragma unroll
        for (int i = 0; i < 4; ++i) {
            int fl = i*512 + t;
            int c = fl >> 4, k = fl & 15;
            uint4 u = *(const uint4*)(vbounce + c*136 + k*8);
            *(uint4*)(vout + ((size_t)(n*CHN + c))*HWSZ + pos0 + k*8) = u;
        }
    }
    {
        float mu = s_mu[pos], rs = s_rs[pos];
        #pragma unroll
        for (int j = 0; j < 32; ++j) {
            int c = cg*32 + j;
            vals[j] = (vals[j] - mu) * rs * lnw[c] + lnb[c];
        }
    }
    __syncthreads();                // vbounce reads done -> pool reusable

    // normalized bf16 tile -> bufB
    #pragma unroll
    for (int k8 = 0; k8 < 4; ++k8) {
        uint4 u;
        u.x = pack2(vals[k8*8+0], vals[k8*8+1]);
        u.y = pack2(vals[k8*8+2], vals[k8*8+3]);
        u.z = pack2(vals[k8*8+4], vals[k8*8+5]);
        u.w = pack2(vals[k8*8+6], vals[k8*8+7]);
        int chunk = cg*4 + k8;
        bufB4[pos*16 + (chunk ^ (pos & 15))] = u;
    }
    stage_w(bufW4, isPan ? w_pp1 : w_mp1, t);
    __syncthreads();

    // ---- GEMM 2: Q projection on normalized input -> NHWC bf16
    #pragma unroll
    for (int i = 0; i < 8; ++i) acc[i] = zero4;
    gemm_tile(bufW4, bufB4, wave, lr, lg, acc);
    epi_nhwc(isPan ? q_pan_t : q_msi_t, isPan ? b_pp1 : b_mp1, n, pos0, wave, lr, lg, acc);

    if (!isPan) {
        // ---- GEMM 3 (msi only): pan_proj1(norm_msi) quirk -> q_pfm, NHWC bf16
        __syncthreads();
        stage_w(bufW4, w_pp1, t);
        __syncthreads();
        #pragma unroll
        for (int i = 0; i < 8; ++i) acc[i] = zero4;
        gemm_tile(bufW4, bufB4, wave, lr, lg, acc);
        epi_nhwc(q_pfm_t, b_pp1, n, pos0, wave, lr, lg, acc);
    }
}

// R7 structure with 4-bit XOR swizzles (conflict-free 16-lane column reads):
//  - S^T QK^T (swapped mfma operands), 2-shuffle softmax, scalar m/l
//  - P rows wave-local: packed uint2 P-stores, NO barrier before PV
//  - 1/l folded into O-bounce; coalesced epilogue
// Barriers: B1(stage) -> QKT+Vstage+softmax -> B2 -> Pwrite+PV -> B3 -> bounce -> B4 -> epi
__global__ __launch_bounds__(512, 2)
void attn_kernel(const unsigned short* __restrict__ ws_u,
                 const float* __restrict__ msi, const float* __restrict__ pan,
                 const float* __restrict__ beta, const float* __restrict__ gamma,
                 float* __restrict__ out)
{
    __shared__ uint4 kp4[4096];     // K [256v][128c] -> P [128w][256v] -> O bounce
    __shared__ uint4 v4[4096];      // V [128c][256v] bf16

    const int t = threadIdx.x;
    const int wave = t >> 6, lane = t & 63, lr = lane & 15, lg = lane >> 4;
    // grid remap: the 4 sibling blocks of an nh land on the SAME XCD (bid%8)
    const int bid = blockIdx.x;
    const int sib = (bid >> 3) & 3;
    const int nh = (bid >> 5) * 8 + (bid & 7);   // 0..1023
    const int path = sib >> 1;
    const int wh = sib & 1;
    const int n = nh >> 8, h = nh & 255;

    const unsigned short* q_msi_t = ws_u;
    const unsigned short* q_pfm_t = ws_u + TENSOR_ELEMS;
    const unsigned short* q_pan_t = ws_u + 2*TENSOR_ELEMS;
    const unsigned short* v_msi   = ws_u + 3*TENSOR_ELEMS;
    const unsigned short* v_pan   = ws_u + 4*TENSOR_ELEMS;

    const unsigned short* Qp = path ? q_pfm_t : q_msi_t;
    const unsigned short* Kp = path ? q_msi_t : q_pan_t;
    const unsigned short* Vp = path ? v_msi   : v_pan;
    const float* resid = path ? pan : msi;
    const float* mul   = path ? gamma : beta;
    float* outp = out + (path ? TENSOR_ELEMS : (size_t)0);

    const size_t qkBase = (size_t)nh * (256*128);   // NHWC row base (elements)
    const unsigned short* vb = Vp + (size_t)n*CHN*HWSZ + (size_t)h*WW;  // V rows (NCHW)

    // ---- stage K (contiguous 64KB) into swizzled LDS
    {
        const uint4* g = (const uint4*)(Kp + qkBase);
        #pragma unroll
        for (int it = 0; it < 8; ++it) {
            int i = it*512 + t;
            int v = i >> 4, ch = i & 15;
            kp4[v*16 + (ch ^ (v & 15))] = g[i];
        }
    }
    // ---- Q fragments: global -> regs (wave owns 16 query positions)
    s16x8 qf[4];
    {
        int w = wh*128 + wave*16 + lr;
        const uint4* g = (const uint4*)(Qp + qkBase + (size_t)w*128);
        #pragma unroll
        for (int ks = 0; ks < 4; ++ks) qf[ks] = __builtin_bit_cast(s16x8, g[ks*4 + lg]);
    }
    __syncthreads();

    // ---- S^T = K Q^T  (wave: 256 v x its 16 w); lane holds S[w=lane&15][v=nt*16+lg*4+r]
    const f32x4 zero4 = {0.f, 0.f, 0.f, 0.f};
    f32x4 sAcc[16];
    #pragma unroll
    for (int i = 0; i < 16; ++i) sAcc[i] = zero4;
    #pragma unroll
    for (int nt = 0; nt < 16; ++nt) {
        int vrow = nt*16 + lr;
        #pragma unroll
        for (int ks = 0; ks < 4; ++ks) {
            s16x8 kf = __builtin_bit_cast(s16x8, kp4[vrow*16 + ((ks*4+lg) ^ (vrow & 15))]);
            sAcc[nt] = __builtin_amdgcn_mfma_f32_16x16x32_bf16(kf, qf[ks], sAcc[nt], 0, 0, 0);
        }
    }

    // ---- stage V into independent region (loads overlap softmax)
    {
        #pragma unroll
        for (int it = 0; it < 8; ++it) {
            int i = it*512 + t;
            int c = i >> 5, ch = i & 31;
            const uint4* g = (const uint4*)(vb + (size_t)c*HWSZ + ch*8);
            v4[c*32 + (ch ^ (c & 15))] = g[0];
        }
    }

    // ---- prefetch residual (fp32, fully coalesced float4) -> 32 regs
    f32x4 rsdA[4], rsdB[4];
    {
        const float* rb = resid + (size_t)n*CHN*HWSZ + (size_t)h*WW + wh*128;
        #pragma unroll
        for (int i = 0; i < 4; ++i) {
            int fl = i*512 + t;
            int c = fl >> 4, k = fl & 15;
            const float* p = rb + (size_t)c*HWSZ + k*8;
            rsdA[i] = *(const f32x4*)p;
            rsdB[i] = *(const f32x4*)(p + 4);
        }
    }

    // ---- softmax over v (lane's own column w = lane&15): scalar m/l, 2 shuffles
    float mx = -1e30f;
    #pragma unroll
    for (int nt = 0; nt < 16; ++nt) {
        #pragma unroll
        for (int r = 0; r < 4; ++r) mx = fmaxf(mx, sAcc[nt][r]);
    }
    mx = fmaxf(mx, __shfl_xor(mx, 16, 64));
    mx = fmaxf(mx, __shfl_xor(mx, 32, 64));
    float sm = 0.f;
    #pragma unroll
    for (int nt = 0; nt < 16; ++nt) {
        #pragma unroll
        for (int r = 0; r < 4; ++r) {
            float p = __expf((sAcc[nt][r] - mx) * SCALE);
            sAcc[nt][r] = p;
            sm += p;
        }
    }
    sm += __shfl_xor(sm, 16, 64);
    sm += __shfl_xor(sm, 32, 64);
    const float inv = 1.0f / sm;

    __syncthreads();                 // QKT reads done (kp4 free) + V staged

    // ---- P (un-normalized) -> own-wave LDS slice: 16 packed uint2 stores
    //      elem = (w*256 + v) ^ ((w&15)<<3), v = nt*16 + lg*4 (+r in-pack)
    {
        unsigned short* pbuf = (unsigned short*)kp4;
        const int wloc = wave*16 + lr;            // this lane's w row
        const int pb_base = wloc*256 + lg*4;
        const int sw = lr << 3;                   // (wloc & 15) << 3
        #pragma unroll
        for (int nt = 0; nt < 16; ++nt) {
            uint2 u;
            u.x = pack2(sAcc[nt][0], sAcc[nt][1]);
            u.y = pack2(sAcc[nt][2], sAcc[nt][3]);
            *(uint2*)(pbuf + ((pb_base + nt*16) ^ sw)) = u;
        }
    }
    // NO barrier: each wave reads only its own P rows (in-wave lgkmcnt ordering)

    // ---- O = V * P^T  (wave: all 128 c x its 16 w, K=256)
    f32x4 oAcc[8];
    #pragma unroll
    for (int i = 0; i < 8; ++i) oAcc[i] = zero4;
    const int wrow = wave*16 + lr;
    #pragma unroll
    for (int ks = 0; ks < 8; ++ks) {
        s16x8 pb = __builtin_bit_cast(s16x8, kp4[wrow*32 + ((ks*4+lg) ^ (wrow & 15))]);
        #pragma unroll
        for (int mt = 0; mt < 8; ++mt) {
            int crow = mt*16 + lr;
            s16x8 av = __builtin_bit_cast(s16x8, v4[crow*32 + ((ks*4+lg) ^ (crow & 15))]);
            oAcc[mt] = __builtin_amdgcn_mfma_f32_16x16x32_bf16(av, pb, oAcc[mt], 0, 0, 0);
        }
    }
    __syncthreads();                 // all PV reads done -> reuse kp4 as O bounce

    // ---- bounce O -> LDS [128c][136w] bf16 (1/l folded in here)
    {
        unsigned short* obuf = (unsigned short*)kp4;
        int wloc = wave*16 + lr;     // 0..127 within this block-half
        #pragma unroll
        for (int mt = 0; mt < 8; ++mt) {
            int cb = mt*16 + lg*4;
            #pragma unroll
            for (int r = 0; r < 4; ++r)
                obuf[(cb + r)*136 + wloc] = f2b(oAcc[mt][r] * inv);
        }
    }
    __syncthreads();

    // ---- coalesced epilogue: out = resid + O * mul[c]
    {
        const unsigned short* obuf = (const unsigned short*)kp4;
        float* ob = outp + (size_t)n*CHN*HWSZ + (size_t)h*WW + wh*128;
        #pragma unroll
        for (int i = 0; i < 4; ++i) {
            int fl = i*512 + t;
            int c = fl >> 4, k = fl & 15;
            uint4 u = *(const uint4*)(obuf + c*136 + k*8);
            float mc = mul[c];
            f32x4 o0, o1;
            o0[0] = rsdA[i][0] + b2f(u.x & 0xffffu) * mc;
            o0[1] = rsdA[i][1] + b2f(u.x >> 16) * mc;
            o0[2] = rsdA[i][2] + b2f(u.y & 0xffffu) * mc;
            o0[3] = rsdA[i][3] + b2f(u.y >> 16) * mc;
            o1[0] = rsdB[i][0] + b2f(u.z & 0xffffu) * mc;
            o1[1] = rsdB[i][1] + b2f(u.z >> 16) * mc;
            o1[2] = rsdB[i][2] + b2f(u.w & 0xffffu) * mc;
            o1[3] = rsdB[i][3] + b2f(u.w >> 16) * mc;
            float* p = ob + (size_t)c*HWSZ + k*8;
            *(f32x4*)p = o0;
            *(f32x4*)(p + 4) = o1;
        }
    }
}

extern "C" void kernel_launch(void* const* d_in, const int* in_sizes, int n_in,
                              void* d_out, int out_size, void* d_ws, size_t ws_size,
                              hipStream_t stream) {
    (void)in_sizes; (void)n_in; (void)out_size; (void)ws_size;
    const float* msi   = (const float*)d_in[0];
    const float* pan   = (const float*)d_in[1];
    const float* lnw_m = (const float*)d_in[2];
    const float* lnb_m = (const float*)d_in[3];
    const float* lnw_p = (const float*)d_in[4];
    const float* lnb_p = (const float*)d_in[5];
    const float* w_mp1 = (const float*)d_in[6];
    const float* b_mp1 = (const float*)d_in[7];
    const float* w_pp1 = (const float*)d_in[8];
    const float* b_pp1 = (const float*)d_in[9];
    const float* w_mp2 = (const float*)d_in[10];
    const float* b_mp2 = (const float*)d_in[11];
    const float* w_pp2 = (const float*)d_in[12];
    const float* b_pp2 = (const float*)d_in[13];
    const float* beta  = (const float*)d_in[14];
    const float* gamma = (const float*)d_in[15];
    unsigned short* ws_u = (unsigned short*)d_ws;
    float* out = (float*)d_out;

    proj_kernel<<<dim3(2048, 2), 512, 0, stream>>>(
        msi, pan, lnw_m, lnb_m, lnw_p, lnb_p,
        w_mp1, b_mp1, w_pp1, b_pp1, w_mp2, b_mp2, w_pp2, b_pp2, ws_u);
    attn_kernel<<<dim3(4096), 512, 0, stream>>>(
        ws_u, msi, pan, beta, gamma, out);
}